// Round 4
// baseline (1177.703 us; speedup 1.0000x reference)
//
#include <hip/hip_runtime.h>
#include <hip/hip_bf16.h>

typedef __bf16 bf16_t;
typedef __bf16 bf16x8 __attribute__((ext_vector_type(8)));
typedef float f32x4 __attribute__((ext_vector_type(4)));

#define MFMA16(A, B, C) __builtin_amdgcn_mfma_f32_16x16x32_bf16(A, B, C, 0, 0, 0)

__device__ __forceinline__ bf16x8 load8_cvt(const float* p) {
    float4 f0 = *(const float4*)p;
    float4 f1 = *(const float4*)(p + 4);
    bf16x8 v = {(bf16_t)f0.x, (bf16_t)f0.y, (bf16_t)f0.z, (bf16_t)f0.w,
                (bf16_t)f1.x, (bf16_t)f1.y, (bf16_t)f1.z, (bf16_t)f1.w};
    return v;
}

// ---------------------------------------------------------------------------
// GEMM: C[M,N] = A[M,K] @ W[N,K]^T + bias[N]
// AT: float (convert during staging) or __bf16 (uint4 copy).
// OT: __bf16 (QKV proj) or float (final out proj). fp32 accum always.
// 128x128 tile, BK=32, 4 waves 2x2, each wave 64x64 (4x4 16x16x32 frags).
// ---------------------------------------------------------------------------
template <typename AT, typename OT>
__global__ __launch_bounds__(256)
void gemm_bt_kernel(const AT* __restrict__ A, const float* __restrict__ W,
                    const float* __restrict__ bias, OT* __restrict__ C,
                    int M, int N, int K)
{
    constexpr int LDT = 40;  // 32 + 8 pad
    __shared__ __align__(16) bf16_t lds_a[128 * LDT];
    __shared__ __align__(16) bf16_t lds_b[128 * LDT];

    const int tid  = threadIdx.x;
    const int wave = tid >> 6;
    const int lane = tid & 63;
    const int l15  = lane & 15;
    const int quad = lane >> 4;
    const int wm   = (wave >> 1) * 64;
    const int wn   = (wave & 1) * 64;

    const int bm = blockIdx.x * 128;
    const int bn = blockIdx.y * 128;

    f32x4 acc[4][4] = {};

    for (int k0 = 0; k0 < K; k0 += 32) {
        for (int i = 0; i < 2; ++i) {
            int c = tid + i * 256;
            int row = c >> 2;
            int col = (c & 3) * 8;
            if constexpr (__is_same(AT, float)) {
                *(bf16x8*)&lds_a[row * LDT + col] =
                    load8_cvt(&A[(size_t)(bm + row) * K + k0 + col]);
            } else {
                *(uint4*)&lds_a[row * LDT + col] =
                    *(const uint4*)&A[(size_t)(bm + row) * K + k0 + col];
            }
            *(bf16x8*)&lds_b[row * LDT + col] =
                load8_cvt(&W[(size_t)(bn + row) * K + k0 + col]);
        }
        __syncthreads();

        bf16x8 af[4], bfr[4];
        for (int i = 0; i < 4; ++i)
            af[i] = *(const bf16x8*)&lds_a[(wm + i * 16 + l15) * LDT + quad * 8];
        for (int j = 0; j < 4; ++j)
            bfr[j] = *(const bf16x8*)&lds_b[(wn + j * 16 + l15) * LDT + quad * 8];
        for (int i = 0; i < 4; ++i)
            for (int j = 0; j < 4; ++j)
                acc[i][j] = MFMA16(af[i], bfr[j], acc[i][j]);
        __syncthreads();
    }

    for (int i = 0; i < 4; ++i) {
        int mrow = bm + wm + i * 16 + quad * 4;
        for (int j = 0; j < 4; ++j) {
            int ncol = bn + wn + j * 16 + l15;
            float bval = bias[ncol];
            for (int r = 0; r < 4; ++r) {
                float v = acc[i][j][r] + bval;
                if constexpr (__is_same(OT, float))
                    C[(size_t)(mrow + r) * N + ncol] = v;
                else
                    C[(size_t)(mrow + r) * N + ncol] = (bf16_t)v;
            }
        }
    }
}

// ---------------------------------------------------------------------------
// RoPE in-place on Q and K (bf16 ws), layout [B*S, H*Dh], pairs (j, j+64).
// ---------------------------------------------------------------------------
__global__ __launch_bounds__(256)
void rope_kernel(bf16_t* __restrict__ Q, bf16_t* __restrict__ Kk)
{
    size_t idx = (size_t)blockIdx.x * 256 + threadIdx.x;
    int j = (int)(idx & 63);
    size_t rest = idx >> 6;
    int h = (int)(rest & 15);
    size_t row = rest >> 4;
    int s = (int)(row & 2047);

    float inv = __expf(-(float)j * 0.14391156831212787f);  // ln(10000)/64
    float ang = (float)s * inv;
    float sn, cs;
    sincosf(ang, &sn, &cs);

    size_t base = row * 2048 + (size_t)h * 128 + j;
    float q0 = (float)Q[base], q1 = (float)Q[base + 64];
    Q[base]      = (bf16_t)(q0 * cs - q1 * sn);
    Q[base + 64] = (bf16_t)(q1 * cs + q0 * sn);
    float k0 = (float)Kk[base], k1 = (float)Kk[base + 64];
    Kk[base]      = (bf16_t)(k0 * cs - k1 * sn);
    Kk[base + 64] = (bf16_t)(k1 * cs + k0 * sn);
}

// ---------------------------------------------------------------------------
// Transpose V [B,S,H*Dh] -> Vt [B,H,Dh,S]  (bf16)
// ---------------------------------------------------------------------------
__global__ __launch_bounds__(256)
void transpose_v(const bf16_t* __restrict__ V, bf16_t* __restrict__ Vt)
{
    __shared__ __align__(16) bf16_t tile[64][72];
    int bh = blockIdx.z;
    int b = bh >> 4, h = bh & 15;
    int t0 = blockIdx.x * 64;
    int d0 = blockIdx.y * 64;
    int tid = threadIdx.x;

    for (int i = 0; i < 2; ++i) {
        int c = tid + i * 256;
        int row = c >> 3, col = (c & 7) * 8;
        *(uint4*)&tile[row][col] =
            *(const uint4*)&V[((size_t)(b * 2048 + t0 + row)) * 2048 + h * 128 + d0 + col];
    }
    __syncthreads();
    for (int i = 0; i < 2; ++i) {
        int c = tid + i * 256;
        int drow = c >> 3, tcol = (c & 7) * 8;
        __align__(16) bf16_t tmp[8];
        for (int j = 0; j < 8; ++j) tmp[j] = tile[tcol + j][drow];
        *(uint4*)&Vt[((size_t)((b * 16 + h) * 128 + d0 + drow)) * 2048 + t0 + tcol] =
            *(uint4*)tmp;
    }
}

// ---------------------------------------------------------------------------
// Flash attention, shuffle-free softmax (all cross-lane via LDS + barriers).
// ---------------------------------------------------------------------------
__global__ __launch_bounds__(256)
void flash_attn(const bf16_t* __restrict__ Q, const bf16_t* __restrict__ Kg,
                const bf16_t* __restrict__ Vt, bf16_t* __restrict__ Ctx)
{
    constexpr int S = 2048, H = 16, Dh = 128, D = 2048;
    constexpr float scale = 0.08838834764831845f;  // 1/sqrt(128)

    __shared__ __align__(16) bf16_t q_lds[64][136];
    __shared__ __align__(16) bf16_t k_lds[32][136];
    __shared__ __align__(16) bf16_t vt_lds[128][40];
    __shared__ float s_lds[4][16][33];
    __shared__ float red_max[4][4][16];
    __shared__ float red_sum[4][4][16];
    __shared__ float alpha_lds[4][16];
    __shared__ float lfin_lds[4][16];

    const int bh = blockIdx.y;
    const int b = bh >> 4, h = bh & 15;
    const int q0 = blockIdx.x * 64;
    const int tid = threadIdx.x, wave = tid >> 6, lane = tid & 63;
    const int l15 = lane & 15, quad = lane >> 4;

    const bf16_t* Qh  = Q  + ((size_t)b * S) * D + h * Dh;
    const bf16_t* Kh  = Kg + ((size_t)b * S) * D + h * Dh;
    const bf16_t* Vth = Vt + ((size_t)(b * H + h)) * Dh * S;

    for (int i = 0; i < 4; ++i) {
        int c = tid + i * 256;
        int row = c >> 4, col = (c & 15) * 8;
        *(uint4*)&q_lds[row][col] = *(const uint4*)&Qh[(size_t)(q0 + row) * D + col];
    }
    __syncthreads();

    bf16x8 aq[4];
    for (int ks = 0; ks < 4; ++ks)
        aq[ks] = *(const bf16x8*)&q_lds[wave * 16 + l15][ks * 32 + quad * 8];

    float m_i = -30000.0f, l_i = 0.0f;
    f32x4 O[8] = {};

    for (int kt = 0; kt < S / 32; ++kt) {
        for (int i = 0; i < 2; ++i) {
            int c = tid + i * 256;
            int row = c >> 4, col = (c & 15) * 8;
            *(uint4*)&k_lds[row][col] =
                *(const uint4*)&Kh[(size_t)(kt * 32 + row) * D + col];
        }
        for (int i = 0; i < 2; ++i) {
            int c = tid + i * 256;
            int row = c >> 2, col = (c & 3) * 8;
            *(uint4*)&vt_lds[row][col] =
                *(const uint4*)&Vth[(size_t)row * S + kt * 32 + col];
        }
        __syncthreads();

        f32x4 sf0 = {}, sf1 = {};
        for (int ks = 0; ks < 4; ++ks) {
            bf16x8 b0 = *(const bf16x8*)&k_lds[l15][ks * 32 + quad * 8];
            bf16x8 b1 = *(const bf16x8*)&k_lds[16 + l15][ks * 32 + quad * 8];
            sf0 = MFMA16(aq[ks], b0, sf0);
            sf1 = MFMA16(aq[ks], b1, sf1);
        }
        for (int r = 0; r < 4; ++r) {
            s_lds[wave][quad * 4 + r][l15]      = sf0[r] * scale;
            s_lds[wave][quad * 4 + r][16 + l15] = sf1[r] * scale;
        }
        __syncthreads();

        float sv[8];
        float pm = -30000.0f;
        for (int j = 0; j < 8; ++j) {
            sv[j] = s_lds[wave][l15][quad * 8 + j];
            pm = fmaxf(pm, sv[j]);
        }
        red_max[wave][quad][l15] = pm;
        __syncthreads();

        float mx = fmaxf(fmaxf(red_max[wave][0][l15], red_max[wave][1][l15]),
                         fmaxf(red_max[wave][2][l15], red_max[wave][3][l15]));
        float mnew  = fmaxf(m_i, mx);
        float alpha = __expf(m_i - mnew);

        bf16x8 ap;
        float ps = 0.f;
        for (int j = 0; j < 8; ++j) {
            bf16_t pb = (bf16_t)__expf(sv[j] - mnew);
            ap[j] = pb;
            ps += (float)pb;
        }
        red_sum[wave][quad][l15] = ps;
        alpha_lds[wave][l15] = alpha;
        __syncthreads();

        float lsum = red_sum[wave][0][l15] + red_sum[wave][1][l15]
                   + red_sum[wave][2][l15] + red_sum[wave][3][l15];
        l_i = l_i * alpha + lsum;
        m_i = mnew;

        float a0 = alpha_lds[wave][quad * 4 + 0];
        float a1 = alpha_lds[wave][quad * 4 + 1];
        float a2 = alpha_lds[wave][quad * 4 + 2];
        float a3 = alpha_lds[wave][quad * 4 + 3];
        for (int j = 0; j < 8; ++j) {
            O[j][0] *= a0; O[j][1] *= a1; O[j][2] *= a2; O[j][3] *= a3;
        }

        for (int j = 0; j < 8; ++j) {
            bf16x8 bv = *(const bf16x8*)&vt_lds[j * 16 + l15][quad * 8];
            O[j] = MFMA16(ap, bv, O[j]);
        }
        __syncthreads();
    }

    lfin_lds[wave][l15] = l_i;
    __syncthreads();

    float linv[4];
    for (int r = 0; r < 4; ++r)
        linv[r] = 1.0f / lfin_lds[wave][quad * 4 + r];

    for (int r = 0; r < 4; ++r) {
        size_t row = q0 + wave * 16 + quad * 4 + r;
        for (int j = 0; j < 8; ++j)
            Ctx[((size_t)b * S + row) * D + h * Dh + j * 16 + l15] =
                (bf16_t)(O[j][r] * linv[r]);
    }
}

// ---------------------------------------------------------------------------
extern "C" void kernel_launch(void* const* d_in, const int* in_sizes, int n_in,
                              void* d_out, int out_size, void* d_ws, size_t ws_size,
                              hipStream_t stream)
{
    // Reference dtypes are float32 -> all I/O is fp32.
    const float* x  = (const float*)d_in[0];
    const float* wq = (const float*)d_in[1];
    const float* bq = (const float*)d_in[2];
    const float* wk = (const float*)d_in[3];
    const float* bk = (const float*)d_in[4];
    const float* wv = (const float*)d_in[5];
    const float* bv = (const float*)d_in[6];
    const float* wo = (const float*)d_in[7];
    const float* bo = (const float*)d_in[8];
    float* out = (float*)d_out;

    const int B = 4, S = 2048, D = 2048, H = 16, Dh = 128;
    const int M = B * S;
    const size_t elems = (size_t)M * D;  // 16,777,216

    // ws (bf16 intermediates): Q | K | V(->Ctx)  = 100.7 MiB.
    // Vt (33.5 MiB bf16) lives in d_out (67 MiB fp32), dead before final GEMM.
    bf16_t* Qw  = (bf16_t*)d_ws;
    bf16_t* Kw  = Qw + elems;
    bf16_t* Vw  = Kw + elems;
    bf16_t* Ctx = Vw;
    bf16_t* Vtw = (bf16_t*)d_out;

    dim3 gGemm(M / 128, D / 128);
    gemm_bt_kernel<float, bf16_t><<<gGemm, 256, 0, stream>>>(x, wq, bq, Qw, M, D, D);
    gemm_bt_kernel<float, bf16_t><<<gGemm, 256, 0, stream>>>(x, wk, bk, Kw, M, D, D);
    gemm_bt_kernel<float, bf16_t><<<gGemm, 256, 0, stream>>>(x, wv, bv, Vw, M, D, D);

    size_t nrope = (size_t)M * H * 64;
    rope_kernel<<<(int)(nrope / 256), 256, 0, stream>>>(Qw, Kw);

    dim3 gT(S / 64, Dh / 64, B * H);
    transpose_v<<<gT, 256, 0, stream>>>(Vw, Vtw);

    dim3 gA(S / 64, B * H);
    flash_attn<<<gA, 256, 0, stream>>>(Qw, Kw, Vtw, Ctx);

    gemm_bt_kernel<bf16_t, float><<<gGemm, 256, 0, stream>>>(Ctx, wo, bo, out, M, D, D);
}